// Round 5
// baseline (1248.390 us; speedup 1.0000x reference)
//
#include <hip/hip_runtime.h>

// ---------------- problem constants ----------------
#define T 4096          // tokens (2*2048)
#define Hdim 1024       // hidden
#define Idim 4096       // intermediate
#define NE 8            // experts
#define OUT0 4194304    // T*Hdim (out elems), logits follow at d_out+OUT0 (T*NE)
#define SPLITK 2        // gemm2 split-K factor (disjoint bf16 partials, no atomics)
#define BK 64           // GEMM K-tile (32 KB LDS total, 2 MFMA k-steps per barrier)

// padded slot capacity: sum ceil(cnt_e/128)*128 <= 8192 + 8*128 = 9216
#define SLOT_CAP 9216

// ---------------- ws layout (bytes) ----------------
#define W1B_OFF 0u                    // bf16 w1 [E][I][H]   67108864
#define W2B_OFF 67108864u             // bf16 w2 [E][H][I]   67108864
#define XB_OFF  134217728u            // bf16 x  [T][H]       8388608
#define HB_OFF  142606336u            // bf16 h  [SLOT_CAP][I] 75497472
#define YB_OFF  218103808u            // bf16 y  [2][SLOT_CAP][H] 37748736
#define META_OFF 255852544u
// meta (int index):
#define M_COUNTS 0      // [8]
#define M_CURS   8      // [8]
#define M_OFFS   16     // [9]
#define M_TEXP   32     // [8192] token-pair -> expert
#define M_TSLOT  8224   // [8192] token-pair -> slot
#define M_STOK   16416  // [9216] slot -> token (-1 = pad)
#define M_TWF    25632  // float[8192] token-pair weight (reinterpret)

typedef short bf16x8 __attribute__((ext_vector_type(8)));
typedef float f32x4  __attribute__((ext_vector_type(4)));

__device__ __forceinline__ unsigned short f2bf(float f) {
    unsigned int b = __float_as_uint(f);
    b += 0x7fffu + ((b >> 16) & 1u);      // round-nearest-even
    return (unsigned short)(b >> 16);
}
__device__ __forceinline__ float bf2f(unsigned short s) {
    return __uint_as_float(((unsigned int)s) << 16);
}

// ---------------- zero meta ----------------
__global__ void zero_k(int* meta) {
    int i = blockIdx.x * blockDim.x + threadIdx.x;
    if (i < 16) meta[i] = 0;                 // counts + cursors
    if (i < SLOT_CAP) meta[M_STOK + i] = -1; // slot_token pad marker
}

// one launch converts both weight tensors fp32->bf16
__global__ void cvt_w_k(const float* __restrict__ w1, const float* __restrict__ w2,
                        unsigned short* __restrict__ w1b, unsigned short* __restrict__ w2b,
                        int n4each) {
    int i = blockIdx.x * blockDim.x + threadIdx.x;
    const float4* src; ushort4* dst; int j;
    if (i < n4each) { src = (const float4*)w1; dst = (ushort4*)w1b; j = i; }
    else            { src = (const float4*)w2; dst = (ushort4*)w2b; j = i - n4each; }
    float4 v = src[j];
    ushort4 o;
    o.x = f2bf(v.x); o.y = f2bf(v.y); o.z = f2bf(v.z); o.w = f2bf(v.w);
    dst[j] = o;
}

// fp32-exact router: logits, top-2, softmax, counts; also emits xb (bf16 x).
__global__ void router_k(const float* __restrict__ x, const float* __restrict__ gw,
                         float* __restrict__ logits_out, int* __restrict__ texp,
                         float* __restrict__ twf, int* __restrict__ counts,
                         unsigned short* __restrict__ xb) {
    int wv = threadIdx.x >> 6, lane = threadIdx.x & 63;
    int t = blockIdx.x * 4 + wv;
    const float* xp = x + (size_t)t * Hdim;
    unsigned short* xbp = xb + (size_t)t * Hdim;
    float s[NE];
    #pragma unroll
    for (int e = 0; e < NE; e++) s[e] = 0.f;
    #pragma unroll
    for (int j = 0; j < 16; j++) {
        float xv = xp[lane + 64 * j];
        xbp[lane + 64 * j] = f2bf(xv);
        #pragma unroll
        for (int e = 0; e < NE; e++) s[e] += xv * gw[e * Hdim + lane + 64 * j];
    }
    #pragma unroll
    for (int e = 0; e < NE; e++) {
        #pragma unroll
        for (int off = 32; off > 0; off >>= 1) s[e] += __shfl_xor(s[e], off);
    }
    if (lane == 0) {
        #pragma unroll
        for (int e = 0; e < NE; e++) logits_out[t * NE + e] = s[e];
        int i0 = 0; float v0 = s[0];
        #pragma unroll
        for (int e = 1; e < NE; e++) if (s[e] > v0) { v0 = s[e]; i0 = e; }
        int i1 = -1; float v1 = -3.4e38f;
        #pragma unroll
        for (int e = 0; e < NE; e++) if (e != i0 && s[e] > v1) { v1 = s[e]; i1 = e; }
        float e1 = expf(v1 - v0);            // v1<=v0, stable
        float inv = 1.f / (1.f + e1);
        texp[2 * t] = i0; texp[2 * t + 1] = i1;
        twf[2 * t] = inv; twf[2 * t + 1] = e1 * inv;
        atomicAdd(&counts[i0], 1);
        atomicAdd(&counts[i1], 1);
    }
}

__global__ void offsets_k(const int* __restrict__ counts, int* __restrict__ offs) {
    if (threadIdx.x == 0 && blockIdx.x == 0) {
        int a = 0; offs[0] = 0;
        for (int e = 0; e < NE; e++) { a += (counts[e] + 127) & ~127; offs[e + 1] = a; }
    }
}

__global__ void assign_k(const int* __restrict__ texp, const int* __restrict__ offs,
                         int* __restrict__ curs, int* __restrict__ stok, int* __restrict__ tslot) {
    int p = blockIdx.x * blockDim.x + threadIdx.x;  // pair id < 8192
    int e = texp[p];
    int slot = offs[e] + atomicAdd(&curs[e], 1);
    stok[slot] = p >> 1;
    tslot[p] = slot;
}

// ---------------- grouped GEMM1: h = gelu(x @ w1[e]^T), bf16 out ----------------
// Register-staged pipeline: buffer loads for tile k+1 issued at TOP of compute
// phase of tile k (in flight behind ds_read+MFMA), so the vmcnt drain at the
// barrier only pays the residual latency — the structural fix global_load_lds
// cannot express (its loads must issue right before the draining barrier).
// LDS: 128xBK64, XOR-swizzled 16B k-chunks (chunk ^ row%8) -> conflict-free.
__global__ __launch_bounds__(256) void gemm1_k(
    const unsigned short* __restrict__ xb, const unsigned short* __restrict__ w1b,
    const int* __restrict__ offs, const int* __restrict__ stok,
    unsigned short* __restrict__ hb) {
    __shared__ __align__(16) unsigned short As[128 * BK];
    __shared__ __align__(16) unsigned short Bs[128 * BK];
    const int rt = blockIdx.y, ct = blockIdx.x;
    const int row0 = rt * 128;
    if (row0 >= offs[NE]) return;
    int e = 0;
    #pragma unroll
    for (int q = 1; q < NE; q++) if (offs[q] <= row0) e = q;

    const int tid = threadIdx.x;
    const int lane = tid & 63, wv = tid >> 6;
    const int srow = lane >> 3;                 // row within 8-row staging group
    const int schunk = (lane & 7) ^ srow;       // swizzled source k-chunk (8 bf16)

    const unsigned short* gA[4]; const unsigned short* gB[4];
    unsigned short *lds_a[4], *lds_b[4];
    #pragma unroll
    for (int i = 0; i < 4; i++) {
        int r = wv * 32 + i * 8 + srow;         // row in 128-tile; r%8 == srow
        int t = stok[row0 + r]; if (t < 0) t = 0;
        gA[i] = xb + (size_t)t * Hdim + schunk * 8;
        gB[i] = w1b + ((size_t)e * Idim + ct * 128 + r) * Hdim + schunk * 8;
        lds_a[i] = As + (wv * 32 + i * 8) * BK + lane * 8;  // same physical layout
        lds_b[i] = Bs + (wv * 32 + i * 8) * BK + lane * 8;  // as the gl_lds version
    }

    f32x4 acc[4][4] = {};
    const int mrow = (wv & 1) * 64, ncol = (wv >> 1) * 64;
    const int fr = lane & 15, qd = lane >> 4;

    // prologue: stage tile 0
    uint4 ra[4], rb[4];
    #pragma unroll
    for (int i = 0; i < 4; i++) { ra[i] = *(const uint4*)(gA[i]); rb[i] = *(const uint4*)(gB[i]); }
    #pragma unroll
    for (int i = 0; i < 4; i++) { *(uint4*)lds_a[i] = ra[i]; *(uint4*)lds_b[i] = rb[i]; }
    __syncthreads();

    const int NIT = Hdim / BK;
    for (int it = 0; it < NIT; it++) {
        if (it + 1 < NIT) {
            const int nk = (it + 1) * BK;
            #pragma unroll
            for (int i = 0; i < 4; i++) {
                ra[i] = *(const uint4*)(gA[i] + nk);   // in flight during compute
                rb[i] = *(const uint4*)(gB[i] + nk);
            }
        }
        #pragma unroll
        for (int ko = 0; ko < 2; ko++) {
            bf16x8 af[4], bff[4];
            #pragma unroll
            for (int mi = 0; mi < 4; mi++)
                af[mi]  = *(const bf16x8*)&As[(mrow + mi * 16 + fr) * BK + ((((ko << 2) | qd) ^ (fr & 7)) << 3)];
            #pragma unroll
            for (int ni = 0; ni < 4; ni++)
                bff[ni] = *(const bf16x8*)&Bs[(ncol + ni * 16 + fr) * BK + ((((ko << 2) | qd) ^ (fr & 7)) << 3)];
            #pragma unroll
            for (int mi = 0; mi < 4; mi++)
                #pragma unroll
                for (int ni = 0; ni < 4; ni++)
                    acc[mi][ni] = __builtin_amdgcn_mfma_f32_16x16x32_bf16(af[mi], bff[ni], acc[mi][ni], 0, 0, 0);
        }
        if (it + 1 < NIT) {
            __syncthreads();     // all waves done reading; drains the (mostly-landed) prefetch
            #pragma unroll
            for (int i = 0; i < 4; i++) { *(uint4*)lds_a[i] = ra[i]; *(uint4*)lds_b[i] = rb[i]; }
            __syncthreads();
        }
    }
    // epilogue: tanh-form gelu (sigmoid identity) -> bf16.
    #pragma unroll
    for (int mi = 0; mi < 4; mi++) {
        #pragma unroll
        for (int ni = 0; ni < 4; ni++) {
            #pragma unroll
            for (int r = 0; r < 4; r++) {
                int row = row0 + mrow + mi * 16 + qd * 4 + r;
                int col = ct * 128 + ncol + ni * 16 + fr;
                float v = acc[mi][ni][r];
                float u = v * (1.f + 0.044715f * v * v);
                float g = v / (1.f + __expf(-1.5957691216f * u));
                hb[(size_t)row * Idim + col] = f2bf(g);
            }
        }
    }
}

// ---------------- grouped GEMM2 (split-K, disjoint partials): yk = h @ w2[e]^T ----------------
// 1D grid 1152, XCD-territory decode: XCD k = id%8 owns rt in [9k, 9k+9) for all
// (ct, kz) -> h fetched once per rt; w2 per-XCD-expert. Same register pipeline.
__global__ __launch_bounds__(256) void gemm2_k(
    const unsigned short* __restrict__ hb, const unsigned short* __restrict__ w2b,
    const int* __restrict__ offs, unsigned short* __restrict__ y16) {
    __shared__ __align__(16) unsigned short As[128 * BK];
    __shared__ __align__(16) unsigned short Bs[128 * BK];
    const int id = blockIdx.x;
    const int k8 = id & 7;                 // intended XCD
    const int j  = id >> 3;                // per-XCD sequence 0..143
    const int ct = j & 7;                  // B col tile
    const int j8 = j >> 3;                 // 0..17
    const int rtL = j8 % 9, kz = j8 / 9;
    const int rt = k8 * 9 + rtL;
    const int row0 = rt * 128;
    if (row0 >= offs[NE]) return;
    int e = 0;
    #pragma unroll
    for (int q = 1; q < NE; q++) if (offs[q] <= row0) e = q;

    const int tid = threadIdx.x;
    const int lane = tid & 63, wv = tid >> 6;
    const int srow = lane >> 3;
    const int schunk = (lane & 7) ^ srow;

    const unsigned short* gA[4]; const unsigned short* gB[4];
    unsigned short *lds_a[4], *lds_b[4];
    #pragma unroll
    for (int i = 0; i < 4; i++) {
        int r = wv * 32 + i * 8 + srow;
        gA[i] = hb + (size_t)(row0 + r) * Idim + schunk * 8;
        gB[i] = w2b + ((size_t)e * Hdim + ct * 128 + r) * Idim + schunk * 8;
        lds_a[i] = As + (wv * 32 + i * 8) * BK + lane * 8;
        lds_b[i] = Bs + (wv * 32 + i * 8) * BK + lane * 8;
    }

    f32x4 acc[4][4] = {};
    const int mrow = (wv & 1) * 64, ncol = (wv >> 1) * 64;
    const int fr = lane & 15, qd = lane >> 4;

    const int k0 = kz * (Idim / SPLITK);
    uint4 ra[4], rb[4];
    #pragma unroll
    for (int i = 0; i < 4; i++) { ra[i] = *(const uint4*)(gA[i] + k0); rb[i] = *(const uint4*)(gB[i] + k0); }
    #pragma unroll
    for (int i = 0; i < 4; i++) { *(uint4*)lds_a[i] = ra[i]; *(uint4*)lds_b[i] = rb[i]; }
    __syncthreads();

    const int NIT = (Idim / SPLITK) / BK;
    for (int it = 0; it < NIT; it++) {
        if (it + 1 < NIT) {
            const int nk = k0 + (it + 1) * BK;
            #pragma unroll
            for (int i = 0; i < 4; i++) {
                ra[i] = *(const uint4*)(gA[i] + nk);
                rb[i] = *(const uint4*)(gB[i] + nk);
            }
        }
        #pragma unroll
        for (int ko = 0; ko < 2; ko++) {
            bf16x8 af[4], bff[4];
            #pragma unroll
            for (int mi = 0; mi < 4; mi++)
                af[mi]  = *(const bf16x8*)&As[(mrow + mi * 16 + fr) * BK + ((((ko << 2) | qd) ^ (fr & 7)) << 3)];
            #pragma unroll
            for (int ni = 0; ni < 4; ni++)
                bff[ni] = *(const bf16x8*)&Bs[(ncol + ni * 16 + fr) * BK + ((((ko << 2) | qd) ^ (fr & 7)) << 3)];
            #pragma unroll
            for (int mi = 0; mi < 4; mi++)
                #pragma unroll
                for (int ni = 0; ni < 4; ni++)
                    acc[mi][ni] = __builtin_amdgcn_mfma_f32_16x16x32_bf16(af[mi], bff[ni], acc[mi][ni], 0, 0, 0);
        }
        if (it + 1 < NIT) {
            __syncthreads();
            #pragma unroll
            for (int i = 0; i < 4; i++) { *(uint4*)lds_a[i] = ra[i]; *(uint4*)lds_b[i] = rb[i]; }
            __syncthreads();
        }
    }
    unsigned short* yk = y16 + (size_t)kz * SLOT_CAP * Hdim;
    #pragma unroll
    for (int mi = 0; mi < 4; mi++) {
        #pragma unroll
        for (int ni = 0; ni < 4; ni++) {
            #pragma unroll
            for (int r = 0; r < 4; r++) {
                int row = row0 + mrow + mi * 16 + qd * 4 + r;
                int col = ct * 128 + ncol + ni * 16 + fr;
                yk[(size_t)row * Hdim + col] = f2bf(acc[mi][ni][r]);
            }
        }
    }
}

// out[t] = w0 * (y0[s0]+y1[s0]) + w1 * (y0[s1]+y1[s1])   (bf16 partials, fused reduce)
__global__ void combine_k(const unsigned short* __restrict__ y16, const int* __restrict__ tslot,
                          const float* __restrict__ twf, float* __restrict__ out) {
    int i = blockIdx.x * blockDim.x + threadIdx.x;   // < T*H/8
    int t = i >> 7, rem = i & 127;                   // H/8 = 128
    int s0 = tslot[2 * t], s1 = tslot[2 * t + 1];
    float w0 = twf[2 * t], w1 = twf[2 * t + 1];
    const uint4* y0 = (const uint4*)(y16);
    const uint4* y1 = (const uint4*)(y16 + (size_t)SLOT_CAP * Hdim);
    uint4 a0 = y0[(size_t)s0 * 128 + rem];
    uint4 a1 = y1[(size_t)s0 * 128 + rem];
    uint4 b0 = y0[(size_t)s1 * 128 + rem];
    uint4 b1 = y1[(size_t)s1 * 128 + rem];
    float o[8];
    #pragma unroll
    for (int j = 0; j < 4; j++) {
        unsigned int ua0 = ((const unsigned int*)&a0)[j], ua1 = ((const unsigned int*)&a1)[j];
        unsigned int ub0 = ((const unsigned int*)&b0)[j], ub1 = ((const unsigned int*)&b1)[j];
        float alo = bf2f((unsigned short)ua0) + bf2f((unsigned short)ua1);
        float ahi = bf2f((unsigned short)(ua0 >> 16)) + bf2f((unsigned short)(ua1 >> 16));
        float blo = bf2f((unsigned short)ub0) + bf2f((unsigned short)ub1);
        float bhi = bf2f((unsigned short)(ub0 >> 16)) + bf2f((unsigned short)(ub1 >> 16));
        o[2 * j]     = w0 * alo + w1 * blo;
        o[2 * j + 1] = w0 * ahi + w1 * bhi;
    }
    float4* out4 = (float4*)out;
    out4[2 * i]     = make_float4(o[0], o[1], o[2], o[3]);
    out4[2 * i + 1] = make_float4(o[4], o[5], o[6], o[7]);
}

extern "C" void kernel_launch(void* const* d_in, const int* in_sizes, int n_in,
                              void* d_out, int out_size, void* d_ws, size_t ws_size,
                              hipStream_t stream) {
    const float* x  = (const float*)d_in[0];   // [2,2048,1024]
    const float* gw = (const float*)d_in[1];   // [8,1024]
    const float* w1 = (const float*)d_in[2];   // [8,4096,1024]
    const float* w2 = (const float*)d_in[3];   // [8,1024,4096]
    float* out = (float*)d_out;

    char* ws = (char*)d_ws;
    unsigned short* w1b = (unsigned short*)(ws + W1B_OFF);
    unsigned short* w2b = (unsigned short*)(ws + W2B_OFF);
    unsigned short* xb  = (unsigned short*)(ws + XB_OFF);
    unsigned short* hb  = (unsigned short*)(ws + HB_OFF);
    unsigned short* y16 = (unsigned short*)(ws + YB_OFF);
    int*            meta = (int*)(ws + META_OFF);
    int* counts = meta + M_COUNTS;
    int* curs   = meta + M_CURS;
    int* offs   = meta + M_OFFS;
    int* texp   = meta + M_TEXP;
    int* tslot  = meta + M_TSLOT;
    int* stok   = meta + M_STOK;
    float* twf  = (float*)(meta + M_TWF);

    zero_k<<<36, 256, 0, stream>>>(meta);
    cvt_w_k<<<65536, 256, 0, stream>>>(w1, w2, w1b, w2b, NE * Idim * Hdim / 4);
    router_k<<<T / 4, 256, 0, stream>>>(x, gw, out + OUT0, texp, twf, counts, xb);
    offsets_k<<<1, 64, 0, stream>>>(counts, offs);
    assign_k<<<32, 256, 0, stream>>>(texp, offs, curs, stok, tslot);
    gemm1_k<<<dim3(Idim / 128, SLOT_CAP / 128), 256, 0, stream>>>(xb, w1b, offs, stok, hb);
    gemm2_k<<<(Hdim / 128) * (SLOT_CAP / 128) * SPLITK, 256, 0, stream>>>(hb, w2b, offs, y16);
    combine_k<<<T * Hdim / 8 / 256, 256, 0, stream>>>(y16, tslot, twf, out);
}

// Round 6
// 631.637 us; speedup vs baseline: 1.9764x; 1.9764x over previous
//
#include <hip/hip_runtime.h>

// ---------------- problem constants ----------------
#define T 4096          // tokens (2*2048)
#define Hdim 1024       // hidden
#define Idim 4096       // intermediate
#define NE 8            // experts
#define OUT0 4194304    // T*Hdim (out elems), logits follow at d_out+OUT0 (T*NE)
#define SPLITK 2        // gemm2 split-K factor (disjoint bf16 partials, no atomics)
#define BK 64           // GEMM K-tile (32 KB LDS total, 2 MFMA k-steps per barrier)

// padded slot capacity: sum ceil(cnt_e/128)*128 <= 8192 + 8*128 = 9216
#define SLOT_CAP 9216

// ---------------- ws layout (bytes) ----------------
#define W1B_OFF 0u                    // bf16 w1 [E][I][H]   67108864
#define W2B_OFF 67108864u             // bf16 w2 [E][H][I]   67108864
#define XB_OFF  134217728u            // bf16 x  [T][H]       8388608
#define HB_OFF  142606336u            // bf16 h  [SLOT_CAP][I] 75497472
#define YB_OFF  218103808u            // bf16 y  [2][SLOT_CAP][H] 37748736
#define META_OFF 255852544u
// meta (int index):
#define M_COUNTS 0      // [8]
#define M_CURS   8      // [8]
#define M_OFFS   16     // [9]
#define M_TEXP   32     // [8192] token-pair -> expert
#define M_TSLOT  8224   // [8192] token-pair -> slot
#define M_STOK   16416  // [9216] slot -> token (-1 = pad)
#define M_TWF    25632  // float[8192] token-pair weight (reinterpret)

typedef short bf16x8 __attribute__((ext_vector_type(8)));
typedef float f32x4  __attribute__((ext_vector_type(4)));

__device__ __forceinline__ unsigned short f2bf(float f) {
    unsigned int b = __float_as_uint(f);
    b += 0x7fffu + ((b >> 16) & 1u);      // round-nearest-even
    return (unsigned short)(b >> 16);
}
__device__ __forceinline__ float bf2f(unsigned short s) {
    return __uint_as_float(((unsigned int)s) << 16);
}

// ---------------- zero meta ----------------
__global__ void zero_k(int* meta) {
    int i = blockIdx.x * blockDim.x + threadIdx.x;
    if (i < 16) meta[i] = 0;                 // counts + cursors
    if (i < SLOT_CAP) meta[M_STOK + i] = -1; // slot_token pad marker
}

// one launch converts both weight tensors fp32->bf16
__global__ void cvt_w_k(const float* __restrict__ w1, const float* __restrict__ w2,
                        unsigned short* __restrict__ w1b, unsigned short* __restrict__ w2b,
                        int n4each) {
    int i = blockIdx.x * blockDim.x + threadIdx.x;
    const float4* src; ushort4* dst; int j;
    if (i < n4each) { src = (const float4*)w1; dst = (ushort4*)w1b; j = i; }
    else            { src = (const float4*)w2; dst = (ushort4*)w2b; j = i - n4each; }
    float4 v = src[j];
    ushort4 o;
    o.x = f2bf(v.x); o.y = f2bf(v.y); o.z = f2bf(v.z); o.w = f2bf(v.w);
    dst[j] = o;
}

// fp32-exact router: logits, top-2, softmax, counts; also emits xb (bf16 x).
__global__ void router_k(const float* __restrict__ x, const float* __restrict__ gw,
                         float* __restrict__ logits_out, int* __restrict__ texp,
                         float* __restrict__ twf, int* __restrict__ counts,
                         unsigned short* __restrict__ xb) {
    int wv = threadIdx.x >> 6, lane = threadIdx.x & 63;
    int t = blockIdx.x * 4 + wv;
    const float* xp = x + (size_t)t * Hdim;
    unsigned short* xbp = xb + (size_t)t * Hdim;
    float s[NE];
    #pragma unroll
    for (int e = 0; e < NE; e++) s[e] = 0.f;
    #pragma unroll
    for (int j = 0; j < 16; j++) {
        float xv = xp[lane + 64 * j];
        xbp[lane + 64 * j] = f2bf(xv);
        #pragma unroll
        for (int e = 0; e < NE; e++) s[e] += xv * gw[e * Hdim + lane + 64 * j];
    }
    #pragma unroll
    for (int e = 0; e < NE; e++) {
        #pragma unroll
        for (int off = 32; off > 0; off >>= 1) s[e] += __shfl_xor(s[e], off);
    }
    if (lane == 0) {
        #pragma unroll
        for (int e = 0; e < NE; e++) logits_out[t * NE + e] = s[e];
        int i0 = 0; float v0 = s[0];
        #pragma unroll
        for (int e = 1; e < NE; e++) if (s[e] > v0) { v0 = s[e]; i0 = e; }
        int i1 = -1; float v1 = -3.4e38f;
        #pragma unroll
        for (int e = 0; e < NE; e++) if (e != i0 && s[e] > v1) { v1 = s[e]; i1 = e; }
        float e1 = expf(v1 - v0);            // v1<=v0, stable
        float inv = 1.f / (1.f + e1);
        texp[2 * t] = i0; texp[2 * t + 1] = i1;
        twf[2 * t] = inv; twf[2 * t + 1] = e1 * inv;
        atomicAdd(&counts[i0], 1);
        atomicAdd(&counts[i1], 1);
    }
}

__global__ void offsets_k(const int* __restrict__ counts, int* __restrict__ offs) {
    if (threadIdx.x == 0 && blockIdx.x == 0) {
        int a = 0; offs[0] = 0;
        for (int e = 0; e < NE; e++) { a += (counts[e] + 127) & ~127; offs[e + 1] = a; }
    }
}

__global__ void assign_k(const int* __restrict__ texp, const int* __restrict__ offs,
                         int* __restrict__ curs, int* __restrict__ stok, int* __restrict__ tslot) {
    int p = blockIdx.x * blockDim.x + threadIdx.x;  // pair id < 8192
    int e = texp[p];
    int slot = offs[e] + atomicAdd(&curs[e], 1);
    stok[slot] = p >> 1;
    tslot[p] = slot;
}

// prefetch macros: individually named uint4 regs (allocator-friendly, no arrays)
#define PF_LOAD(base_off) \
    pa0 = *(const uint4*)(gA0 + (base_off)); pa1 = *(const uint4*)(gA1 + (base_off)); \
    pa2 = *(const uint4*)(gA2 + (base_off)); pa3 = *(const uint4*)(gA3 + (base_off)); \
    pb0 = *(const uint4*)(gB0 + (base_off)); pb1 = *(const uint4*)(gB1 + (base_off)); \
    pb2 = *(const uint4*)(gB2 + (base_off)); pb3 = *(const uint4*)(gB3 + (base_off));
#define PF_STORE() \
    *(uint4*)la0 = pa0; *(uint4*)la1 = pa1; *(uint4*)la2 = pa2; *(uint4*)la3 = pa3; \
    *(uint4*)lb0 = pb0; *(uint4*)lb1 = pb1; *(uint4*)lb2 = pb2; *(uint4*)lb3 = pb3;

// ---------------- grouped GEMM1: h = gelu(x @ w1[e]^T), bf16 out ----------------
// Register-staged pipeline: buffer loads for tile k+1 issued at TOP of compute
// phase of tile k (in flight behind ds_read+MFMA). __launch_bounds__(256,2)
// floors the VGPR budget at 256/wave so the prefetch regs are NOT spilled to
// scratch (round-5 failure mode: 84-VGPR target -> 780 MB scratch traffic).
// LDS: 128xBK64, XOR-swizzled 16B k-chunks (chunk ^ row%8) -> conflict-free.
__global__ __launch_bounds__(256, 2) void gemm1_k(
    const unsigned short* __restrict__ xb, const unsigned short* __restrict__ w1b,
    const int* __restrict__ offs, const int* __restrict__ stok,
    unsigned short* __restrict__ hb) {
    __shared__ __align__(16) unsigned short As[128 * BK];
    __shared__ __align__(16) unsigned short Bs[128 * BK];
    const int rt = blockIdx.y, ct = blockIdx.x;
    const int row0 = rt * 128;
    if (row0 >= offs[NE]) return;
    int e = 0;
    #pragma unroll
    for (int q = 1; q < NE; q++) if (offs[q] <= row0) e = q;

    const int tid = threadIdx.x;
    const int lane = tid & 63, wv = tid >> 6;
    const int srow = lane >> 3;                 // row within 8-row staging group
    const int schunk = (lane & 7) ^ srow;       // swizzled source k-chunk (8 bf16)

    int r0 = wv * 32 + 0 * 8 + srow, r1 = wv * 32 + 1 * 8 + srow;
    int r2 = wv * 32 + 2 * 8 + srow, r3 = wv * 32 + 3 * 8 + srow;
    int t0 = stok[row0 + r0]; if (t0 < 0) t0 = 0;
    int t1 = stok[row0 + r1]; if (t1 < 0) t1 = 0;
    int t2 = stok[row0 + r2]; if (t2 < 0) t2 = 0;
    int t3 = stok[row0 + r3]; if (t3 < 0) t3 = 0;
    const unsigned short* gA0 = xb + (size_t)t0 * Hdim + schunk * 8;
    const unsigned short* gA1 = xb + (size_t)t1 * Hdim + schunk * 8;
    const unsigned short* gA2 = xb + (size_t)t2 * Hdim + schunk * 8;
    const unsigned short* gA3 = xb + (size_t)t3 * Hdim + schunk * 8;
    const unsigned short* gB0 = w1b + ((size_t)e * Idim + ct * 128 + r0) * Hdim + schunk * 8;
    const unsigned short* gB1 = w1b + ((size_t)e * Idim + ct * 128 + r1) * Hdim + schunk * 8;
    const unsigned short* gB2 = w1b + ((size_t)e * Idim + ct * 128 + r2) * Hdim + schunk * 8;
    const unsigned short* gB3 = w1b + ((size_t)e * Idim + ct * 128 + r3) * Hdim + schunk * 8;
    unsigned short* la0 = As + (wv * 32 + 0 * 8) * BK + lane * 8;
    unsigned short* la1 = As + (wv * 32 + 1 * 8) * BK + lane * 8;
    unsigned short* la2 = As + (wv * 32 + 2 * 8) * BK + lane * 8;
    unsigned short* la3 = As + (wv * 32 + 3 * 8) * BK + lane * 8;
    unsigned short* lb0 = Bs + (wv * 32 + 0 * 8) * BK + lane * 8;
    unsigned short* lb1 = Bs + (wv * 32 + 1 * 8) * BK + lane * 8;
    unsigned short* lb2 = Bs + (wv * 32 + 2 * 8) * BK + lane * 8;
    unsigned short* lb3 = Bs + (wv * 32 + 3 * 8) * BK + lane * 8;

    f32x4 acc[4][4] = {};
    const int mrow = (wv & 1) * 64, ncol = (wv >> 1) * 64;
    const int fr = lane & 15, qd = lane >> 4;

    uint4 pa0, pa1, pa2, pa3, pb0, pb1, pb2, pb3;
    PF_LOAD(0)
    PF_STORE()
    __syncthreads();

    const int NIT = Hdim / BK;
    for (int it = 0; it < NIT; it++) {
        if (it + 1 < NIT) { PF_LOAD((it + 1) * BK) }   // in flight during compute
        #pragma unroll
        for (int ko = 0; ko < 2; ko++) {
            bf16x8 af[4], bff[4];
            #pragma unroll
            for (int mi = 0; mi < 4; mi++)
                af[mi]  = *(const bf16x8*)&As[(mrow + mi * 16 + fr) * BK + ((((ko << 2) | qd) ^ (fr & 7)) << 3)];
            #pragma unroll
            for (int ni = 0; ni < 4; ni++)
                bff[ni] = *(const bf16x8*)&Bs[(ncol + ni * 16 + fr) * BK + ((((ko << 2) | qd) ^ (fr & 7)) << 3)];
            #pragma unroll
            for (int mi = 0; mi < 4; mi++)
                #pragma unroll
                for (int ni = 0; ni < 4; ni++)
                    acc[mi][ni] = __builtin_amdgcn_mfma_f32_16x16x32_bf16(af[mi], bff[ni], acc[mi][ni], 0, 0, 0);
        }
        if (it + 1 < NIT) {
            __syncthreads();     // waves done reading; prefetch has had full compute phase to land
            PF_STORE()
            __syncthreads();
        }
    }
    // epilogue: tanh-form gelu (sigmoid identity) -> bf16.
    #pragma unroll
    for (int mi = 0; mi < 4; mi++) {
        #pragma unroll
        for (int ni = 0; ni < 4; ni++) {
            #pragma unroll
            for (int r = 0; r < 4; r++) {
                int row = row0 + mrow + mi * 16 + qd * 4 + r;
                int col = ct * 128 + ncol + ni * 16 + fr;
                float v = acc[mi][ni][r];
                float u = v * (1.f + 0.044715f * v * v);
                float g = v / (1.f + __expf(-1.5957691216f * u));
                hb[(size_t)row * Idim + col] = f2bf(g);
            }
        }
    }
}

// ---------------- grouped GEMM2 (split-K, disjoint partials): yk = h @ w2[e]^T ----------------
// 1D grid 1152, XCD-territory decode: XCD k = id%8 owns rt in [9k, 9k+9) for all
// (ct, kz) -> h fetched once per rt; w2 per-XCD-expert. Same register pipeline.
__global__ __launch_bounds__(256, 2) void gemm2_k(
    const unsigned short* __restrict__ hb, const unsigned short* __restrict__ w2b,
    const int* __restrict__ offs, unsigned short* __restrict__ y16) {
    __shared__ __align__(16) unsigned short As[128 * BK];
    __shared__ __align__(16) unsigned short Bs[128 * BK];
    const int id = blockIdx.x;
    const int k8 = id & 7;                 // intended XCD
    const int j  = id >> 3;                // per-XCD sequence 0..143
    const int ct = j & 7;                  // B col tile
    const int j8 = j >> 3;                 // 0..17
    const int rtL = j8 % 9, kz = j8 / 9;
    const int rt = k8 * 9 + rtL;
    const int row0 = rt * 128;
    if (row0 >= offs[NE]) return;
    int e = 0;
    #pragma unroll
    for (int q = 1; q < NE; q++) if (offs[q] <= row0) e = q;

    const int tid = threadIdx.x;
    const int lane = tid & 63, wv = tid >> 6;
    const int srow = lane >> 3;
    const int schunk = (lane & 7) ^ srow;

    int r0 = wv * 32 + 0 * 8 + srow, r1 = wv * 32 + 1 * 8 + srow;
    int r2 = wv * 32 + 2 * 8 + srow, r3 = wv * 32 + 3 * 8 + srow;
    const unsigned short* gA0 = hb + (size_t)(row0 + r0) * Idim + schunk * 8;
    const unsigned short* gA1 = hb + (size_t)(row0 + r1) * Idim + schunk * 8;
    const unsigned short* gA2 = hb + (size_t)(row0 + r2) * Idim + schunk * 8;
    const unsigned short* gA3 = hb + (size_t)(row0 + r3) * Idim + schunk * 8;
    const unsigned short* gB0 = w2b + ((size_t)e * Hdim + ct * 128 + r0) * Idim + schunk * 8;
    const unsigned short* gB1 = w2b + ((size_t)e * Hdim + ct * 128 + r1) * Idim + schunk * 8;
    const unsigned short* gB2 = w2b + ((size_t)e * Hdim + ct * 128 + r2) * Idim + schunk * 8;
    const unsigned short* gB3 = w2b + ((size_t)e * Hdim + ct * 128 + r3) * Idim + schunk * 8;
    unsigned short* la0 = As + (wv * 32 + 0 * 8) * BK + lane * 8;
    unsigned short* la1 = As + (wv * 32 + 1 * 8) * BK + lane * 8;
    unsigned short* la2 = As + (wv * 32 + 2 * 8) * BK + lane * 8;
    unsigned short* la3 = As + (wv * 32 + 3 * 8) * BK + lane * 8;
    unsigned short* lb0 = Bs + (wv * 32 + 0 * 8) * BK + lane * 8;
    unsigned short* lb1 = Bs + (wv * 32 + 1 * 8) * BK + lane * 8;
    unsigned short* lb2 = Bs + (wv * 32 + 2 * 8) * BK + lane * 8;
    unsigned short* lb3 = Bs + (wv * 32 + 3 * 8) * BK + lane * 8;

    f32x4 acc[4][4] = {};
    const int mrow = (wv & 1) * 64, ncol = (wv >> 1) * 64;
    const int fr = lane & 15, qd = lane >> 4;

    const int k0 = kz * (Idim / SPLITK);
    uint4 pa0, pa1, pa2, pa3, pb0, pb1, pb2, pb3;
    PF_LOAD(k0)
    PF_STORE()
    __syncthreads();

    const int NIT = (Idim / SPLITK) / BK;
    for (int it = 0; it < NIT; it++) {
        if (it + 1 < NIT) { PF_LOAD(k0 + (it + 1) * BK) }
        #pragma unroll
        for (int ko = 0; ko < 2; ko++) {
            bf16x8 af[4], bff[4];
            #pragma unroll
            for (int mi = 0; mi < 4; mi++)
                af[mi]  = *(const bf16x8*)&As[(mrow + mi * 16 + fr) * BK + ((((ko << 2) | qd) ^ (fr & 7)) << 3)];
            #pragma unroll
            for (int ni = 0; ni < 4; ni++)
                bff[ni] = *(const bf16x8*)&Bs[(ncol + ni * 16 + fr) * BK + ((((ko << 2) | qd) ^ (fr & 7)) << 3)];
            #pragma unroll
            for (int mi = 0; mi < 4; mi++)
                #pragma unroll
                for (int ni = 0; ni < 4; ni++)
                    acc[mi][ni] = __builtin_amdgcn_mfma_f32_16x16x32_bf16(af[mi], bff[ni], acc[mi][ni], 0, 0, 0);
        }
        if (it + 1 < NIT) {
            __syncthreads();
            PF_STORE()
            __syncthreads();
        }
    }
    unsigned short* yk = y16 + (size_t)kz * SLOT_CAP * Hdim;
    #pragma unroll
    for (int mi = 0; mi < 4; mi++) {
        #pragma unroll
        for (int ni = 0; ni < 4; ni++) {
            #pragma unroll
            for (int r = 0; r < 4; r++) {
                int row = row0 + mrow + mi * 16 + qd * 4 + r;
                int col = ct * 128 + ncol + ni * 16 + fr;
                yk[(size_t)row * Hdim + col] = f2bf(acc[mi][ni][r]);
            }
        }
    }
}

// out[t] = w0 * (y0[s0]+y1[s0]) + w1 * (y0[s1]+y1[s1])   (bf16 partials, fused reduce)
__global__ void combine_k(const unsigned short* __restrict__ y16, const int* __restrict__ tslot,
                          const float* __restrict__ twf, float* __restrict__ out) {
    int i = blockIdx.x * blockDim.x + threadIdx.x;   // < T*H/8
    int t = i >> 7, rem = i & 127;                   // H/8 = 128
    int s0 = tslot[2 * t], s1 = tslot[2 * t + 1];
    float w0 = twf[2 * t], w1 = twf[2 * t + 1];
    const uint4* y0 = (const uint4*)(y16);
    const uint4* y1 = (const uint4*)(y16 + (size_t)SLOT_CAP * Hdim);
    uint4 a0 = y0[(size_t)s0 * 128 + rem];
    uint4 a1 = y1[(size_t)s0 * 128 + rem];
    uint4 b0 = y0[(size_t)s1 * 128 + rem];
    uint4 b1 = y1[(size_t)s1 * 128 + rem];
    float o[8];
    #pragma unroll
    for (int j = 0; j < 4; j++) {
        unsigned int ua0 = ((const unsigned int*)&a0)[j], ua1 = ((const unsigned int*)&a1)[j];
        unsigned int ub0 = ((const unsigned int*)&b0)[j], ub1 = ((const unsigned int*)&b1)[j];
        float alo = bf2f((unsigned short)ua0) + bf2f((unsigned short)ua1);
        float ahi = bf2f((unsigned short)(ua0 >> 16)) + bf2f((unsigned short)(ua1 >> 16));
        float blo = bf2f((unsigned short)ub0) + bf2f((unsigned short)ub1);
        float bhi = bf2f((unsigned short)(ub0 >> 16)) + bf2f((unsigned short)(ub1 >> 16));
        o[2 * j]     = w0 * alo + w1 * blo;
        o[2 * j + 1] = w0 * ahi + w1 * bhi;
    }
    float4* out4 = (float4*)out;
    out4[2 * i]     = make_float4(o[0], o[1], o[2], o[3]);
    out4[2 * i + 1] = make_float4(o[4], o[5], o[6], o[7]);
}

extern "C" void kernel_launch(void* const* d_in, const int* in_sizes, int n_in,
                              void* d_out, int out_size, void* d_ws, size_t ws_size,
                              hipStream_t stream) {
    const float* x  = (const float*)d_in[0];   // [2,2048,1024]
    const float* gw = (const float*)d_in[1];   // [8,1024]
    const float* w1 = (const float*)d_in[2];   // [8,4096,1024]
    const float* w2 = (const float*)d_in[3];   // [8,1024,4096]
    float* out = (float*)d_out;

    char* ws = (char*)d_ws;
    unsigned short* w1b = (unsigned short*)(ws + W1B_OFF);
    unsigned short* w2b = (unsigned short*)(ws + W2B_OFF);
    unsigned short* xb  = (unsigned short*)(ws + XB_OFF);
    unsigned short* hb  = (unsigned short*)(ws + HB_OFF);
    unsigned short* y16 = (unsigned short*)(ws + YB_OFF);
    int*            meta = (int*)(ws + META_OFF);
    int* counts = meta + M_COUNTS;
    int* curs   = meta + M_CURS;
    int* offs   = meta + M_OFFS;
    int* texp   = meta + M_TEXP;
    int* tslot  = meta + M_TSLOT;
    int* stok   = meta + M_STOK;
    float* twf  = (float*)(meta + M_TWF);

    zero_k<<<36, 256, 0, stream>>>(meta);
    cvt_w_k<<<65536, 256, 0, stream>>>(w1, w2, w1b, w2b, NE * Idim * Hdim / 4);
    router_k<<<T / 4, 256, 0, stream>>>(x, gw, out + OUT0, texp, twf, counts, xb);
    offsets_k<<<1, 64, 0, stream>>>(counts, offs);
    assign_k<<<32, 256, 0, stream>>>(texp, offs, curs, stok, tslot);
    gemm1_k<<<dim3(Idim / 128, SLOT_CAP / 128), 256, 0, stream>>>(xb, w1b, offs, stok, hb);
    gemm2_k<<<(Hdim / 128) * (SLOT_CAP / 128) * SPLITK, 256, 0, stream>>>(hb, w2b, offs, y16);
    combine_k<<<T * Hdim / 8 / 256, 256, 0, stream>>>(y16, tslot, twf, out);
}